// Round 6
// baseline (195.029 us; speedup 1.0000x reference)
//
#include <hip/hip_runtime.h>
#include <hip/hip_bf16.h>
#include <stdint.h>

typedef __hip_bfloat16 bf16;
typedef __attribute__((ext_vector_type(8))) short bf16x8;
typedef __attribute__((ext_vector_type(4))) float f32x4;
typedef __attribute__((ext_vector_type(16))) float f32x16;

#define MFMA16(a,b,c) __builtin_amdgcn_mfma_f32_16x16x32_bf16((a),(b),(c),0,0,0)
#define MFMA32(a,b,c) __builtin_amdgcn_mfma_f32_32x32x16_bf16((a),(b),(c),0,0,0)

#define B_ 2
#define T_ 2048
#define E_ 1024
#define H_ 16
#define D_ 64
#define M_ (B_*T_)   // 4096
#define PROJ_ELEMS (32ull * 2048ull * 64ull)   // 4.19M elems per Q/K/V tensor

__device__ __forceinline__ void gload_lds16(const bf16* g, bf16* l) {
  __builtin_amdgcn_global_load_lds(
      (const __attribute__((address_space(1))) unsigned int*)g,
      (__attribute__((address_space(3))) unsigned int*)l,
      16, 0, 0);
}

// ---------------- pre-pass: f32 -> bf16 convert ----------------
__global__ __launch_bounds__(256) void cvt_x_kernel(const float* __restrict__ in,
                                                    bf16* __restrict__ out) {
  int i = blockIdx.x * 256 + threadIdx.x;        // each thread: 4 floats
  float4 v = reinterpret_cast<const float4*>(in)[i];
  union { bf16 h[4]; unsigned long long u; } t;
  t.h[0] = __float2bfloat16(v.x);
  t.h[1] = __float2bfloat16(v.y);
  t.h[2] = __float2bfloat16(v.z);
  t.h[3] = __float2bfloat16(v.w);
  reinterpret_cast<unsigned long long*>(out)[i] = t.u;
}

// ---------------- pre-pass: 4x W [K][N] f32 -> Wt [N][K] bf16 (fused) ----------------
__global__ __launch_bounds__(256) void transpose_cvt4_kernel(
    const float* __restrict__ W0, const float* __restrict__ W1,
    const float* __restrict__ W2, const float* __restrict__ W3,
    bf16* __restrict__ T0, bf16* __restrict__ T1,
    bf16* __restrict__ T2, bf16* __restrict__ T3) {
  __shared__ float tile[32][33];
  const float* W; bf16* Wt;
  switch (blockIdx.z) {
    case 0: W = W0; Wt = T0; break;
    case 1: W = W1; Wt = T1; break;
    case 2: W = W2; Wt = T2; break;
    default: W = W3; Wt = T3; break;
  }
  const int tx = threadIdx.x, ty = threadIdx.y;  // 32 x 8
  const int n0 = blockIdx.x * 32, k0 = blockIdx.y * 32;
#pragma unroll
  for (int i = 0; i < 4; i++)
    tile[ty + 8*i][tx] = W[(size_t)(k0 + ty + 8*i) * E_ + n0 + tx];
  __syncthreads();
#pragma unroll
  for (int i = 0; i < 4; i++)
    Wt[(size_t)(n0 + ty + 8*i) * E_ + k0 + tx] = __float2bfloat16(tile[tx][ty + 8*i]);
}

// ---------------- GEMM: C[M=4096][N] = A[M][K] * Bt[N][K]^T ----------------
__global__ __launch_bounds__(256) void gemm_bt_kernel(
    const bf16* __restrict__ A, const bf16* __restrict__ Bt,
    void* __restrict__ out, const float* __restrict__ bias,
    const int mode, const float scale)
{
  constexpr int K = E_;
  __shared__ __align__(16) bf16 As[128*32];
  __shared__ __align__(16) bf16 Bs[128*32];
  const int tid = threadIdx.x;
  const int w = tid >> 6, l = tid & 63;
  const int lc = l & 15, lr = l >> 4;
  const int m0 = blockIdx.y * 128, n0 = blockIdx.x * 128;
  const int wr = (w >> 1) * 64, wc = (w & 1) * 64;

  f32x4 acc[4][4];
#pragma unroll
  for (int m = 0; m < 4; m++)
#pragma unroll
    for (int n = 0; n < 4; n++) acc[m][n] = (f32x4)0.0f;

  const int srow = l >> 2;            // 0..15
  const int scol = (l & 3) * 8;       // k element offset

  for (int k0 = 0; k0 < K; k0 += 32) {
#pragma unroll
    for (int p = 0; p < 2; p++) {
      const int r = (w*2 + p) * 16 + srow;
      gload_lds16(A  + (size_t)(m0 + r) * K + k0 + scol, &As[(w*2 + p) * 512]);
      gload_lds16(Bt + (size_t)(n0 + r) * K + k0 + scol, &Bs[(w*2 + p) * 512]);
    }
    __syncthreads();
    bf16x8 af[4], bfr[4];
#pragma unroll
    for (int m = 0; m < 4; m++)
      af[m] = *reinterpret_cast<const bf16x8*>(&As[(wr + m*16 + lc) * 32 + lr * 8]);
#pragma unroll
    for (int n = 0; n < 4; n++)
      bfr[n] = *reinterpret_cast<const bf16x8*>(&Bs[(wc + n*16 + lc) * 32 + lr * 8]);
#pragma unroll
    for (int m = 0; m < 4; m++)
#pragma unroll
      for (int n = 0; n < 4; n++)
        acc[m][n] = MFMA16(af[m], bfr[n], acc[m][n]);
    __syncthreads();
  }

  const int proj = blockIdx.x >> 3;   // uniform per block (mode 3)
#pragma unroll
  for (int m = 0; m < 4; m++) {
#pragma unroll
    for (int n = 0; n < 4; n++) {
#pragma unroll
      for (int j = 0; j < 4; j++) {
        const int row = m0 + wr + m*16 + lr*4 + j;   // token index
        const int col = n0 + wc + n*16 + lc;         // output feature
        if (mode == 2) {
          reinterpret_cast<float*>(out)[(size_t)row * E_ + col] = acc[m][n][j] + bias[col];
        } else {
          const int cp = col & (E_-1);
          const int b = row >> 11, t = row & (T_-1);
          const int h = cp >> 6,  d = cp & (D_-1);
          const float v = acc[m][n][j] * (proj == 0 ? scale : 1.0f);
          size_t idx;
          if (proj == 2) idx = (((size_t)(b*H_ + h)) * D_ + d) * T_ + t;      // V transposed
          else           idx = (((size_t)(b*H_ + h)) * T_ + t) * D_ + d;      // Q, K
          reinterpret_cast<bf16*>(out)[proj * PROJ_ELEMS + idx] = __float2bfloat16(v);
        }
      }
    }
  }
}

// ---------------- flash attention (causal), swapped-QK^T, split-K ----------------
// Q,K: [B*H][T][D] bf16 (Q pre-scaled by D^-0.5 * log2(e)). Vt: [B*H][D][T] bf16.
// O: [B*T][E] bf16.
// Grid: 2048 blocks x 128 thr (2 warps). Block = (bh, qt); the two warps split
// the k-tile range of the same 32-row q-tile (split-K flash). Partials merged
// via LDS (warp1 writes {m,l,O~}; warp0 merges, normalizes, writes O).
// qt dispatched descending (LPT). bh XCD-pinned via bid&7 (4 heads/XCD -> 2MB L2 set).
// Defer-max (T13): skip O-rescale when all lanes' tile max grew <= 8 (base-2).
__global__ __launch_bounds__(128, 4) void attn_fwd_kernel(
    const bf16* __restrict__ Q, const bf16* __restrict__ Kt,
    const bf16* __restrict__ Vt, bf16* __restrict__ O)
{
  __shared__ float Lm[32];
  __shared__ float Ll[32];
  __shared__ float Lo[64 * 33];      // O~1 [d][q], stride 33 (conflict-free)

  const int tid = threadIdx.x;
  const int w = tid >> 6, l = tid & 63;
  const int ln = l & 31;             // q-col / k-row / d-row lane index
  const int hi = l >> 5;
  const int bid = blockIdx.x;
  const int bh  = (bid & 7) * 4 + ((bid >> 3) & 3);
  const int qt  = 63 - (bid >> 5);   // 0..63, biggest-work first (LPT)
  const int q0  = qt * 32;

  const bf16* Qb = Q  + (size_t)bh * T_ * D_;
  const bf16* kp = Kt + (size_t)bh * T_ * D_ + (size_t)ln * D_ + hi*8;
  const bf16* vp = Vt + (size_t)bh * D_ * T_ + (size_t)ln * T_ + hi*8;

  // Q as B-operand: qf[s] covers d = s*16 + hi*8 + 0..7 of row q0+ln
  bf16x8 qf[4];
#pragma unroll
  for (int s = 0; s < 4; s++)
    qf[s] = *reinterpret_cast<const bf16x8*>(
        &Qb[(size_t)(q0 + ln) * D_ + s*16 + hi*8]);

  f32x16 oacc0 = (f32x16)0.0f, oacc1 = (f32x16)0.0f;
  float mrow = -1e30f, psum = 0.0f;

  bf16x8 kA[4], vA[2][2], kB[4], vB[2][2];

#define LOADKV(KK, VV, KT) do {                                              \
    _Pragma("unroll")                                                        \
    for (int s_ = 0; s_ < 4; s_++)                                           \
      KK[s_] = *reinterpret_cast<const bf16x8*>(                             \
          kp + (size_t)(KT)*32*D_ + s_*16);                                  \
    _Pragma("unroll")                                                        \
    for (int a_ = 0; a_ < 2; a_++)                                           \
      _Pragma("unroll")                                                      \
      for (int s_ = 0; s_ < 2; s_++)                                         \
        VV[a_][s_] = *reinterpret_cast<const bf16x8*>(                       \
            vp + (size_t)a_*32*T_ + (KT)*32 + s_*16);                        \
  } while (0)

  union U4 { uint32_t u[4]; bf16x8 v; };
  union PK { bf16 h[2]; uint32_t u; };

#define TILE_BODY(KK, VV, KKN, VVN, KT, PRE, MASK) do {                      \
    if (PRE) { LOADKV(KKN, VVN, (KT)+1); }                                   \
    f32x16 sT = (f32x16)0.0f;                                                \
    _Pragma("unroll")                                                        \
    for (int s_ = 0; s_ < 4; s_++) sT = MFMA32(KK[s_], qf[s_], sT);          \
    if (MASK) {                                                              \
      _Pragma("unroll")                                                      \
      for (int r_ = 0; r_ < 16; r_++) {                                      \
        const int mm = (r_&3) + 8*(r_>>2) + 4*hi;                            \
        if (mm > ln) sT[r_] = -1e30f;                                        \
      }                                                                      \
    }                                                                        \
    float tmax = fmaxf(fmaxf(fmaxf(sT[0],sT[1]), fmaxf(sT[2],sT[3])),        \
                       fmaxf(fmaxf(sT[4],sT[5]), fmaxf(sT[6],sT[7])));       \
    tmax = fmaxf(tmax,                                                       \
           fmaxf(fmaxf(fmaxf(sT[8],sT[9]),  fmaxf(sT[10],sT[11])),           \
                 fmaxf(fmaxf(sT[12],sT[13]),fmaxf(sT[14],sT[15]))));         \
    tmax = fmaxf(tmax, __shfl_xor(tmax, 32));                                \
    if (!__all(tmax <= mrow + 8.0f)) {                                       \
      const float mn_ = fmaxf(mrow, tmax);                                   \
      const float fsc = exp2f(mrow - mn_);                                   \
      mrow = mn_;                                                            \
      psum *= fsc;                                                           \
      oacc0 *= fsc;                                                          \
      oacc1 *= fsc;                                                          \
    }                                                                        \
    _Pragma("unroll")                                                        \
    for (int r_ = 0; r_ < 16; r_++) {                                        \
      const float pe = exp2f(sT[r_] - mrow);                                 \
      sT[r_] = pe;                                                           \
      psum += pe;                                                            \
    }                                                                        \
    uint32_t u_[8];                                                          \
    _Pragma("unroll")                                                        \
    for (int i_ = 0; i_ < 8; i_++) {                                         \
      PK pk_;                                                                \
      pk_.h[0] = __float2bfloat16(sT[2*i_]);                                 \
      pk_.h[1] = __float2bfloat16(sT[2*i_+1]);                               \
      u_[i_] = pk_.u;                                                        \
    }                                                                        \
    const uint32_t x0 = __shfl_xor(hi ? u_[0] : u_[2], 32);                  \
    const uint32_t x1 = __shfl_xor(hi ? u_[1] : u_[3], 32);                  \
    const uint32_t x2 = __shfl_xor(hi ? u_[4] : u_[6], 32);                  \
    const uint32_t x3 = __shfl_xor(hi ? u_[5] : u_[7], 32);                  \
    U4 pf0, pf1;                                                             \
    pf0.u[0] = hi ? x0 : u_[0];  pf0.u[1] = hi ? x1 : u_[1];                 \
    pf0.u[2] = hi ? u_[2] : x0;  pf0.u[3] = hi ? u_[3] : x1;                 \
    pf1.u[0] = hi ? x2 : u_[4];  pf1.u[1] = hi ? x3 : u_[5];                 \
    pf1.u[2] = hi ? u_[6] : x2;  pf1.u[3] = hi ? u_[7] : x3;                 \
    oacc0 = MFMA32(VV[0][0], pf0.v, oacc0);                                  \
    oacc0 = MFMA32(VV[0][1], pf1.v, oacc0);                                  \
    oacc1 = MFMA32(VV[1][0], pf0.v, oacc1);                                  \
    oacc1 = MFMA32(VV[1][1], pf1.v, oacc1);                                  \
  } while (0)

  // ---- split-K ranges: warp0 -> [0,h), warp1 -> [h, qt+1) (owns diagonal) ----
  const int nkt = qt + 1;
  const int h = nkt >> 1;
  const int kt_lo = w ? h : 0;
  const int kt_hi = w ? nkt : h;

  if (kt_lo < kt_hi) {
    LOADKV(kA, vA, kt_lo);
    int kt = kt_lo;
    while (kt + 2 <= kt_hi) {
      TILE_BODY(kA, vA, kB, vB, kt, true, false);
      if (kt + 2 == kt_hi) {
        if (kt + 1 == qt) TILE_BODY(kB, vB, kA, vA, kt+1, false, true);
        else              TILE_BODY(kB, vB, kA, vA, kt+1, false, false);
      } else {
        TILE_BODY(kB, vB, kA, vA, kt+1, true, false);
      }
      kt += 2;
    }
    if (kt < kt_hi) {
      if (kt == qt) TILE_BODY(kA, vA, kB, vB, kt, false, true);
      else          TILE_BODY(kA, vA, kB, vB, kt, false, false);
    }
  }

  // ---- full row sum across hi halves ----
  psum += __shfl_xor(psum, 32);

  // ---- warp1 publishes partials ----
  if (w == 1) {
    if (hi == 0) { Lm[ln] = mrow; Ll[ln] = psum; }
#pragma unroll
    for (int r = 0; r < 16; r++) {
      const int d = (r&3) + 8*(r>>2) + 4*hi;
      Lo[d * 33 + ln] = oacc0[r];
      Lo[(32 + d) * 33 + ln] = oacc1[r];
    }
  }
  __syncthreads();

  // ---- warp0 merges and writes O ----
  if (w == 0) {
    const float m1 = Lm[ln], l1 = Ll[ln];
    const float mn = fmaxf(mrow, m1);
    const float f0 = exp2f(mrow - mn);
    const float f1 = exp2f(m1 - mn);
    const float inv = 1.0f / (psum * f0 + l1 * f1);
    const int b = bh >> 4, hh = bh & 15;
    const size_t rowbase = (size_t)(b * T_ + q0 + ln) * E_ + hh * 64;
#pragma unroll
    for (int r = 0; r < 16; r++) {
      const int d = (r&3) + 8*(r>>2) + 4*hi;
      O[rowbase + d]      = __float2bfloat16((oacc0[r]*f0 + Lo[d*33 + ln]*f1) * inv);
      O[rowbase + 32 + d] = __float2bfloat16((oacc1[r]*f0 + Lo[(32+d)*33 + ln]*f1) * inv);
    }
  }
#undef TILE_BODY
#undef LOADKV
}

// ---------------- launch ----------------
extern "C" void kernel_launch(void* const* d_in, const int* in_sizes, int n_in,
                              void* d_out, int out_size, void* d_ws, size_t ws_size,
                              hipStream_t stream) {
  const float* x  = (const float*)d_in[0];
  const float* Wq = (const float*)d_in[1];
  const float* Wk = (const float*)d_in[2];
  const float* Wv = (const float*)d_in[3];
  const float* Wo = (const float*)d_in[4];
  const float* bo = (const float*)d_in[5];
  float* out = (float*)d_out;

  char* ws = (char*)d_ws;
  bf16* xb  = (bf16*)(ws);                         // 8 MB  [4096][1024]
  bf16* WqT = (bf16*)(ws + (8ull  << 20));         // 2 MB  [N][K]  (Wq|Wk|Wv contiguous)
  bf16* WkT = (bf16*)(ws + (10ull << 20));
  bf16* WvT = (bf16*)(ws + (12ull << 20));
  bf16* WoT = (bf16*)(ws + (14ull << 20));
  bf16* Qb  = (bf16*)(ws + (16ull << 20));         // 8 MB [BH][T][D]; K,V follow contiguous
  bf16* Ob  = (bf16*)(ws + (40ull << 20));         // 8 MB  [4096][1024]

  cvt_x_kernel<<<4096, 256, 0, stream>>>(x, xb);
  transpose_cvt4_kernel<<<dim3(32, 32, 4), dim3(32, 8), 0, stream>>>(
      Wq, Wk, Wv, Wo, WqT, WkT, WvT, WoT);

  // fused QKV projection: N = 3072, Bt = [WqT|WkT|WvT] contiguous
  const float qscale = 0.125f * 1.44269504f;       // D^-0.5 * log2(e)
  gemm_bt_kernel<<<dim3(24, 32), 256, 0, stream>>>(xb, WqT, Qb, nullptr, 3, qscale);

  attn_fwd_kernel<<<2048, 128, 0, stream>>>(
      Qb, Qb + PROJ_ELEMS, Qb + 2*PROJ_ELEMS, Ob);

  gemm_bt_kernel<<<dim3(8, 32), 256, 0, stream>>>(Ob, WoT, out, bo, 2, 1.0f);
}

// Round 7
// 153.372 us; speedup vs baseline: 1.2716x; 1.2716x over previous
//
#include <hip/hip_runtime.h>
#include <hip/hip_bf16.h>
#include <stdint.h>

typedef __hip_bfloat16 bf16;
typedef __attribute__((ext_vector_type(8))) short bf16x8;
typedef __attribute__((ext_vector_type(4))) float f32x4;
typedef __attribute__((ext_vector_type(16))) float f32x16;

#define MFMA16(a,b,c) __builtin_amdgcn_mfma_f32_16x16x32_bf16((a),(b),(c),0,0,0)
#define MFMA32(a,b,c) __builtin_amdgcn_mfma_f32_32x32x16_bf16((a),(b),(c),0,0,0)

#define B_ 2
#define T_ 2048
#define E_ 1024
#define H_ 16
#define D_ 64
#define M_ (B_*T_)   // 4096
#define PROJ_ELEMS (32ull * 2048ull * 64ull)   // 4.19M elems per Q/K/V tensor

__device__ __forceinline__ void gload_lds16(const bf16* g, bf16* l) {
  __builtin_amdgcn_global_load_lds(
      (const __attribute__((address_space(1))) unsigned int*)g,
      (__attribute__((address_space(3))) unsigned int*)l,
      16, 0, 0);
}

// ---------------- pre-pass: f32 -> bf16 convert ----------------
__global__ __launch_bounds__(256) void cvt_x_kernel(const float* __restrict__ in,
                                                    bf16* __restrict__ out) {
  int i = blockIdx.x * 256 + threadIdx.x;        // each thread: 4 floats
  float4 v = reinterpret_cast<const float4*>(in)[i];
  union { bf16 h[4]; unsigned long long u; } t;
  t.h[0] = __float2bfloat16(v.x);
  t.h[1] = __float2bfloat16(v.y);
  t.h[2] = __float2bfloat16(v.z);
  t.h[3] = __float2bfloat16(v.w);
  reinterpret_cast<unsigned long long*>(out)[i] = t.u;
}

// ---------------- pre-pass: 4x W [K][N] f32 -> Wt [N][K] bf16 (fused) ----------------
__global__ __launch_bounds__(256) void transpose_cvt4_kernel(
    const float* __restrict__ W0, const float* __restrict__ W1,
    const float* __restrict__ W2, const float* __restrict__ W3,
    bf16* __restrict__ T0, bf16* __restrict__ T1,
    bf16* __restrict__ T2, bf16* __restrict__ T3) {
  __shared__ float tile[32][33];
  const float* W; bf16* Wt;
  switch (blockIdx.z) {
    case 0: W = W0; Wt = T0; break;
    case 1: W = W1; Wt = T1; break;
    case 2: W = W2; Wt = T2; break;
    default: W = W3; Wt = T3; break;
  }
  const int tx = threadIdx.x, ty = threadIdx.y;  // 32 x 8
  const int n0 = blockIdx.x * 32, k0 = blockIdx.y * 32;
#pragma unroll
  for (int i = 0; i < 4; i++)
    tile[ty + 8*i][tx] = W[(size_t)(k0 + ty + 8*i) * E_ + n0 + tx];
  __syncthreads();
#pragma unroll
  for (int i = 0; i < 4; i++)
    Wt[(size_t)(n0 + ty + 8*i) * E_ + k0 + tx] = __float2bfloat16(tile[tx][ty + 8*i]);
}

// ---------------- GEMM: C[M=4096][N] = A[M][K] * Bt[N][K]^T ----------------
__global__ __launch_bounds__(256) void gemm_bt_kernel(
    const bf16* __restrict__ A, const bf16* __restrict__ Bt,
    void* __restrict__ out, const float* __restrict__ bias,
    const int mode, const float scale)
{
  constexpr int K = E_;
  __shared__ __align__(16) bf16 As[128*32];
  __shared__ __align__(16) bf16 Bs[128*32];
  const int tid = threadIdx.x;
  const int w = tid >> 6, l = tid & 63;
  const int lc = l & 15, lr = l >> 4;
  const int m0 = blockIdx.y * 128, n0 = blockIdx.x * 128;
  const int wr = (w >> 1) * 64, wc = (w & 1) * 64;

  f32x4 acc[4][4];
#pragma unroll
  for (int m = 0; m < 4; m++)
#pragma unroll
    for (int n = 0; n < 4; n++) acc[m][n] = (f32x4)0.0f;

  const int srow = l >> 2;            // 0..15
  const int scol = (l & 3) * 8;       // k element offset

  for (int k0 = 0; k0 < K; k0 += 32) {
#pragma unroll
    for (int p = 0; p < 2; p++) {
      const int r = (w*2 + p) * 16 + srow;
      gload_lds16(A  + (size_t)(m0 + r) * K + k0 + scol, &As[(w*2 + p) * 512]);
      gload_lds16(Bt + (size_t)(n0 + r) * K + k0 + scol, &Bs[(w*2 + p) * 512]);
    }
    __syncthreads();
    bf16x8 af[4], bfr[4];
#pragma unroll
    for (int m = 0; m < 4; m++)
      af[m] = *reinterpret_cast<const bf16x8*>(&As[(wr + m*16 + lc) * 32 + lr * 8]);
#pragma unroll
    for (int n = 0; n < 4; n++)
      bfr[n] = *reinterpret_cast<const bf16x8*>(&Bs[(wc + n*16 + lc) * 32 + lr * 8]);
#pragma unroll
    for (int m = 0; m < 4; m++)
#pragma unroll
      for (int n = 0; n < 4; n++)
        acc[m][n] = MFMA16(af[m], bfr[n], acc[m][n]);
    __syncthreads();
  }

  const int proj = blockIdx.x >> 3;   // uniform per block (mode 3)
#pragma unroll
  for (int m = 0; m < 4; m++) {
#pragma unroll
    for (int n = 0; n < 4; n++) {
#pragma unroll
      for (int j = 0; j < 4; j++) {
        const int row = m0 + wr + m*16 + lr*4 + j;   // token index
        const int col = n0 + wc + n*16 + lc;         // output feature
        if (mode == 2) {
          reinterpret_cast<float*>(out)[(size_t)row * E_ + col] = acc[m][n][j] + bias[col];
        } else {
          const int cp = col & (E_-1);
          const int b = row >> 11, t = row & (T_-1);
          const int h = cp >> 6,  d = cp & (D_-1);
          const float v = acc[m][n][j] * (proj == 0 ? scale : 1.0f);
          size_t idx;
          if (proj == 2) idx = (((size_t)(b*H_ + h)) * D_ + d) * T_ + t;      // V transposed
          else           idx = (((size_t)(b*H_ + h)) * T_ + t) * D_ + d;      // Q, K
          reinterpret_cast<bf16*>(out)[proj * PROJ_ELEMS + idx] = __float2bfloat16(v);
        }
      }
    }
  }
}

// ---------------- flash attention (causal), swapped-QK^T, split-K ----------------
// Q,K: [B*H][T][D] bf16 (Q pre-scaled by D^-0.5 * log2(e)). Vt: [B*H][D][T] bf16.
// O: [B*T][E] bf16.
// Grid: 2048 blocks x 128 thr (2 warps). Block = (bh, qt); the two warps split
// the k-tile range of the same 32-row q-tile (split-K flash). Partials merged
// via LDS (warp1 writes {m,l,O~}; warp0 merges, normalizes, writes O).
// qt dispatched descending (LPT). bh XCD-pinned via bid&7 (4 heads/XCD -> 2MB L2 set).
// Defer-max (T13): skip O-rescale when all lanes' tile max grew <= 8 (base-2).
// NOTE: launch_bounds MUST stay (128,2): (128,4) makes the allocator target the
// 64-VGPR tier -> K/V reg-dbuf spills to scratch (r6: FETCH 3x, attn 78->124us).
__global__ __launch_bounds__(128, 2) void attn_fwd_kernel(
    const bf16* __restrict__ Q, const bf16* __restrict__ Kt,
    const bf16* __restrict__ Vt, bf16* __restrict__ O)
{
  __shared__ float Lm[32];
  __shared__ float Ll[32];
  __shared__ float Lo[64 * 33];      // O~1 [d][q], stride 33 (conflict-free)

  const int tid = threadIdx.x;
  const int w = tid >> 6, l = tid & 63;
  const int ln = l & 31;             // q-col / k-row / d-row lane index
  const int hi = l >> 5;
  const int bid = blockIdx.x;
  const int bh  = (bid & 7) * 4 + ((bid >> 3) & 3);
  const int qt  = 63 - (bid >> 5);   // 0..63, biggest-work first (LPT)
  const int q0  = qt * 32;

  const bf16* Qb = Q  + (size_t)bh * T_ * D_;
  const bf16* kp = Kt + (size_t)bh * T_ * D_ + (size_t)ln * D_ + hi*8;
  const bf16* vp = Vt + (size_t)bh * D_ * T_ + (size_t)ln * T_ + hi*8;

  // Q as B-operand: qf[s] covers d = s*16 + hi*8 + 0..7 of row q0+ln
  bf16x8 qf[4];
#pragma unroll
  for (int s = 0; s < 4; s++)
    qf[s] = *reinterpret_cast<const bf16x8*>(
        &Qb[(size_t)(q0 + ln) * D_ + s*16 + hi*8]);

  f32x16 oacc0 = (f32x16)0.0f, oacc1 = (f32x16)0.0f;
  float mrow = -1e30f, psum = 0.0f;

  bf16x8 kA[4], vA[2][2], kB[4], vB[2][2];

#define LOADKV(KK, VV, KT) do {                                              \
    _Pragma("unroll")                                                        \
    for (int s_ = 0; s_ < 4; s_++)                                           \
      KK[s_] = *reinterpret_cast<const bf16x8*>(                             \
          kp + (size_t)(KT)*32*D_ + s_*16);                                  \
    _Pragma("unroll")                                                        \
    for (int a_ = 0; a_ < 2; a_++)                                           \
      _Pragma("unroll")                                                      \
      for (int s_ = 0; s_ < 2; s_++)                                         \
        VV[a_][s_] = *reinterpret_cast<const bf16x8*>(                       \
            vp + (size_t)a_*32*T_ + (KT)*32 + s_*16);                        \
  } while (0)

  union U4 { uint32_t u[4]; bf16x8 v; };
  union PK { bf16 h[2]; uint32_t u; };

#define TILE_BODY(KK, VV, KKN, VVN, KT, PRE, MASK) do {                      \
    if (PRE) { LOADKV(KKN, VVN, (KT)+1); }                                   \
    f32x16 sT = (f32x16)0.0f;                                                \
    _Pragma("unroll")                                                        \
    for (int s_ = 0; s_ < 4; s_++) sT = MFMA32(KK[s_], qf[s_], sT);          \
    if (MASK) {                                                              \
      _Pragma("unroll")                                                      \
      for (int r_ = 0; r_ < 16; r_++) {                                      \
        const int mm = (r_&3) + 8*(r_>>2) + 4*hi;                            \
        if (mm > ln) sT[r_] = -1e30f;                                        \
      }                                                                      \
    }                                                                        \
    float tmax = fmaxf(fmaxf(fmaxf(sT[0],sT[1]), fmaxf(sT[2],sT[3])),        \
                       fmaxf(fmaxf(sT[4],sT[5]), fmaxf(sT[6],sT[7])));       \
    tmax = fmaxf(tmax,                                                       \
           fmaxf(fmaxf(fmaxf(sT[8],sT[9]),  fmaxf(sT[10],sT[11])),           \
                 fmaxf(fmaxf(sT[12],sT[13]),fmaxf(sT[14],sT[15]))));         \
    tmax = fmaxf(tmax, __shfl_xor(tmax, 32));                                \
    if (!__all(tmax <= mrow + 8.0f)) {                                       \
      const float mn_ = fmaxf(mrow, tmax);                                   \
      const float fsc = exp2f(mrow - mn_);                                   \
      mrow = mn_;                                                            \
      psum *= fsc;                                                           \
      oacc0 *= fsc;                                                          \
      oacc1 *= fsc;                                                          \
    }                                                                        \
    _Pragma("unroll")                                                        \
    for (int r_ = 0; r_ < 16; r_++) {                                        \
      const float pe = exp2f(sT[r_] - mrow);                                 \
      sT[r_] = pe;                                                           \
      psum += pe;                                                            \
    }                                                                        \
    uint32_t u_[8];                                                          \
    _Pragma("unroll")                                                        \
    for (int i_ = 0; i_ < 8; i_++) {                                         \
      PK pk_;                                                                \
      pk_.h[0] = __float2bfloat16(sT[2*i_]);                                 \
      pk_.h[1] = __float2bfloat16(sT[2*i_+1]);                               \
      u_[i_] = pk_.u;                                                        \
    }                                                                        \
    const uint32_t x0 = __shfl_xor(hi ? u_[0] : u_[2], 32);                  \
    const uint32_t x1 = __shfl_xor(hi ? u_[1] : u_[3], 32);                  \
    const uint32_t x2 = __shfl_xor(hi ? u_[4] : u_[6], 32);                  \
    const uint32_t x3 = __shfl_xor(hi ? u_[5] : u_[7], 32);                  \
    U4 pf0, pf1;                                                             \
    pf0.u[0] = hi ? x0 : u_[0];  pf0.u[1] = hi ? x1 : u_[1];                 \
    pf0.u[2] = hi ? u_[2] : x0;  pf0.u[3] = hi ? u_[3] : x1;                 \
    pf1.u[0] = hi ? x2 : u_[4];  pf1.u[1] = hi ? x3 : u_[5];                 \
    pf1.u[2] = hi ? u_[6] : x2;  pf1.u[3] = hi ? u_[7] : x3;                 \
    oacc0 = MFMA32(VV[0][0], pf0.v, oacc0);                                  \
    oacc0 = MFMA32(VV[0][1], pf1.v, oacc0);                                  \
    oacc1 = MFMA32(VV[1][0], pf0.v, oacc1);                                  \
    oacc1 = MFMA32(VV[1][1], pf1.v, oacc1);                                  \
  } while (0)

  // ---- split-K ranges: warp0 -> [0,h), warp1 -> [h, qt+1) (owns diagonal) ----
  const int nkt = qt + 1;
  const int h = nkt >> 1;
  const int kt_lo = w ? h : 0;
  const int kt_hi = w ? nkt : h;

  if (kt_lo < kt_hi) {
    LOADKV(kA, vA, kt_lo);
    int kt = kt_lo;
    while (kt + 2 <= kt_hi) {
      TILE_BODY(kA, vA, kB, vB, kt, true, false);
      if (kt + 2 == kt_hi) {
        if (kt + 1 == qt) TILE_BODY(kB, vB, kA, vA, kt+1, false, true);
        else              TILE_BODY(kB, vB, kA, vA, kt+1, false, false);
      } else {
        TILE_BODY(kB, vB, kA, vA, kt+1, true, false);
      }
      kt += 2;
    }
    if (kt < kt_hi) {
      if (kt == qt) TILE_BODY(kA, vA, kB, vB, kt, false, true);
      else          TILE_BODY(kA, vA, kB, vB, kt, false, false);
    }
  }

  // ---- full row sum across hi halves ----
  psum += __shfl_xor(psum, 32);

  // ---- warp1 publishes partials ----
  if (w == 1) {
    if (hi == 0) { Lm[ln] = mrow; Ll[ln] = psum; }
#pragma unroll
    for (int r = 0; r < 16; r++) {
      const int d = (r&3) + 8*(r>>2) + 4*hi;
      Lo[d * 33 + ln] = oacc0[r];
      Lo[(32 + d) * 33 + ln] = oacc1[r];
    }
  }
  __syncthreads();

  // ---- warp0 merges and writes O ----
  if (w == 0) {
    const float m1 = Lm[ln], l1 = Ll[ln];
    const float mn = fmaxf(mrow, m1);
    const float f0 = exp2f(mrow - mn);
    const float f1 = exp2f(m1 - mn);
    const float inv = 1.0f / (psum * f0 + l1 * f1);
    const int b = bh >> 4, hh = bh & 15;
    const size_t rowbase = (size_t)(b * T_ + q0 + ln) * E_ + hh * 64;
#pragma unroll
    for (int r = 0; r < 16; r++) {
      const int d = (r&3) + 8*(r>>2) + 4*hi;
      O[rowbase + d]      = __float2bfloat16((oacc0[r]*f0 + Lo[d*33 + ln]*f1) * inv);
      O[rowbase + 32 + d] = __float2bfloat16((oacc1[r]*f0 + Lo[(32+d)*33 + ln]*f1) * inv);
    }
  }
#undef TILE_BODY
#undef LOADKV
}

// ---------------- launch ----------------
extern "C" void kernel_launch(void* const* d_in, const int* in_sizes, int n_in,
                              void* d_out, int out_size, void* d_ws, size_t ws_size,
                              hipStream_t stream) {
  const float* x  = (const float*)d_in[0];
  const float* Wq = (const float*)d_in[1];
  const float* Wk = (const float*)d_in[2];
  const float* Wv = (const float*)d_in[3];
  const float* Wo = (const float*)d_in[4];
  const float* bo = (const float*)d_in[5];
  float* out = (float*)d_out;

  char* ws = (char*)d_ws;
  bf16* xb  = (bf16*)(ws);                         // 8 MB  [4096][1024]
  bf16* WqT = (bf16*)(ws + (8ull  << 20));         // 2 MB  [N][K]  (Wq|Wk|Wv contiguous)
  bf16* WkT = (bf16*)(ws + (10ull << 20));
  bf16* WvT = (bf16*)(ws + (12ull << 20));
  bf16* WoT = (bf16*)(ws + (14ull << 20));
  bf16* Qb  = (bf16*)(ws + (16ull << 20));         // 8 MB [BH][T][D]; K,V follow contiguous
  bf16* Ob  = (bf16*)(ws + (40ull << 20));         // 8 MB  [4096][1024]

  cvt_x_kernel<<<4096, 256, 0, stream>>>(x, xb);
  transpose_cvt4_kernel<<<dim3(32, 32, 4), dim3(32, 8), 0, stream>>>(
      Wq, Wk, Wv, Wo, WqT, WkT, WvT, WoT);

  // fused QKV projection: N = 3072, Bt = [WqT|WkT|WvT] contiguous
  const float qscale = 0.125f * 1.44269504f;       // D^-0.5 * log2(e)
  gemm_bt_kernel<<<dim3(24, 32), 256, 0, stream>>>(xb, WqT, Qb, nullptr, 3, qscale);

  attn_fwd_kernel<<<2048, 128, 0, stream>>>(
      Qb, Qb + PROJ_ELEMS, Qb + 2*PROJ_ELEMS, Ob);

  gemm_bt_kernel<<<dim3(8, 32), 256, 0, stream>>>(Ob, WoT, out, bo, 2, 1.0f);
}